// Round 1
// baseline (2422.406 us; speedup 1.0000x reference)
//
#include <hip/hip_runtime.h>
#include <hip/hip_bf16.h>

#define BB   16
#define CC   64
#define SS   64
#define HH   32
#define WW   32
#define HWHW 1024
#define CD   32
#define QELEMS (BB * CD * SS * HWHW) /* 33554432 elems per q/k/v tensor */

typedef unsigned short ushort_t;

static __device__ inline float bf2f(ushort_t u) {
    union { float f; unsigned int i; } v;
    v.i = ((unsigned int)u) << 16;
    return v.f;
}
static __device__ inline ushort_t f2bf(float f) {
    union { float f; unsigned int i; } v;
    v.f = f;
    unsigned int x = v.i;
    return (ushort_t)((x + 0x7fffu + ((x >> 16) & 1u)) >> 16);
}

// ---------------------------------------------------------------------------
// Kernel 1: fused q/k/v conv (1x3x3, pad (0,1,1)), fp32 compute, bf16 store.
// Grid: (B*S, 12) — blockIdx.y selects 8 of the 96 concatenated out-channels.
// ---------------------------------------------------------------------------
__global__ __launch_bounds__(256) void conv_qkv_kernel(
    const float* __restrict__ x,
    const float* __restrict__ wq, const float* __restrict__ bq,
    const float* __restrict__ wk, const float* __restrict__ bk,
    const float* __restrict__ wv, const float* __restrict__ bv,
    ushort_t* __restrict__ qkv)
{
    __shared__ float xs[34][34];   // zero-padded plane; borders stay zero

    const int tid = threadIdx.x;
    const int bs  = blockIdx.x;          // b*S + s
    const int b   = bs >> 6;
    const int s   = bs & 63;
    const int g   = blockIdx.y;          // 0..11
    const int gsel = g >> 2;             // 0=q, 1=k, 2=v
    const int cdb  = (g & 3) * 8;        // out-channel base within tensor

    const float* wsel = (gsel == 0) ? wq : (gsel == 1) ? wk : wv;
    const float* bsel = (gsel == 0) ? bq : (gsel == 1) ? bk : bv;
    ushort_t* outbase = qkv + (size_t)gsel * QELEMS;

    for (int i = tid; i < 34 * 34; i += 256) ((float*)xs)[i] = 0.0f;

    float acc[8][4];
#pragma unroll
    for (int oc = 0; oc < 8; ++oc)
#pragma unroll
        for (int p = 0; p < 4; ++p) acc[oc][p] = 0.0f;

    const int pix0 = tid * 4;
    const int h0 = pix0 >> 5;
    const int w0 = pix0 & 31;

    const float* xplane0 = x + ((size_t)b * CC * SS + s) * HWHW;

    for (int c = 0; c < CC; ++c) {
        __syncthreads();
        const float4 xv = *(const float4*)(xplane0 + (size_t)c * SS * HWHW + pix0);
        xs[h0 + 1][w0 + 1] = xv.x;
        xs[h0 + 1][w0 + 2] = xv.y;
        xs[h0 + 1][w0 + 3] = xv.z;
        xs[h0 + 1][w0 + 4] = xv.w;
        __syncthreads();

        float win[3][6];
#pragma unroll
        for (int r = 0; r < 3; ++r)
#pragma unroll
            for (int cc2 = 0; cc2 < 6; ++cc2)
                win[r][cc2] = xs[h0 + r][w0 + cc2];

#pragma unroll
        for (int oc = 0; oc < 8; ++oc) {
            const float* wr = wsel + ((size_t)(cdb + oc) * CC + c) * 9;
            const float w00 = wr[0], w01 = wr[1], w02 = wr[2];
            const float w10 = wr[3], w11 = wr[4], w12 = wr[5];
            const float w20 = wr[6], w21 = wr[7], w22 = wr[8];
#pragma unroll
            for (int p = 0; p < 4; ++p) {
                float a = acc[oc][p];
                a += w00 * win[0][p + 0] + w01 * win[0][p + 1] + w02 * win[0][p + 2];
                a += w10 * win[1][p + 0] + w11 * win[1][p + 1] + w12 * win[1][p + 2];
                a += w20 * win[2][p + 0] + w21 * win[2][p + 1] + w22 * win[2][p + 2];
                acc[oc][p] = a;
            }
        }
    }

#pragma unroll
    for (int oc = 0; oc < 8; ++oc) {
        const float bias = bsel[cdb + oc];
        ushort4 u;
        u.x = f2bf(acc[oc][0] + bias);
        u.y = f2bf(acc[oc][1] + bias);
        u.z = f2bf(acc[oc][2] + bias);
        u.w = f2bf(acc[oc][3] + bias);
        ushort_t* op = outbase + (((size_t)b * CD + cdb + oc) * SS + s) * HWHW + pix0;
        *(ushort4*)op = u;
    }
}

// ---------------------------------------------------------------------------
// Kernel 2: per-(b,c) attention: scores = sigmoid(q k^T /32); out = scores v.
// One block per (b,c). Output overwrites the q slot (bf16).
// ---------------------------------------------------------------------------
__global__ __launch_bounds__(256) void attn_kernel(ushort_t* __restrict__ qkv)
{
    __shared__ float    scb[64][65];
    __shared__ ushort_t qch[64][132];   // +4 pad to break bank stride
    __shared__ ushort_t kch[64][132];

    const int tid = threadIdx.x;
    const int bc  = blockIdx.x;                       // b*CD + cd
    ushort_t* qbase = qkv + (size_t)bc * SS * HWHW;
    const ushort_t* kbase = qbase + QELEMS;
    const ushort_t* vbase = qbase + 2 * (size_t)QELEMS;

    const int ty = tid >> 4, tx = tid & 15;
    const int sy = ty * 4, sx = tx * 4;

    float acc[4][4];
#pragma unroll
    for (int i = 0; i < 4; ++i)
#pragma unroll
        for (int j = 0; j < 4; ++j) acc[i][j] = 0.0f;

    // ---- phase 1: QK^T over f-chunks of 128 ----
    for (int fc = 0; fc < 8; ++fc) {
        __syncthreads();
#pragma unroll
        for (int u = 0; u < 8; ++u) {
            const int unit = tid + u * 256;        // 0..2047 (8B units)
            const int row  = unit >> 5;
            const int col  = (unit & 31) * 4;
            const ushort4 qa = *(const ushort4*)(qbase + (size_t)row * HWHW + fc * 128 + col);
            const ushort4 ka = *(const ushort4*)(kbase + (size_t)row * HWHW + fc * 128 + col);
            *(ushort4*)&qch[row][col] = qa;
            *(ushort4*)&kch[row][col] = ka;
        }
        __syncthreads();

        for (int f = 0; f < 128; f += 2) {
            float q0[4], q1[4], k0[4], k1[4];
#pragma unroll
            for (int i = 0; i < 4; ++i) {
                const unsigned int qp = *(const unsigned int*)&qch[sy + i][f];
                q0[i] = bf2f((ushort_t)(qp & 0xffffu));
                q1[i] = bf2f((ushort_t)(qp >> 16));
                const unsigned int kp = *(const unsigned int*)&kch[sx + i][f];
                k0[i] = bf2f((ushort_t)(kp & 0xffffu));
                k1[i] = bf2f((ushort_t)(kp >> 16));
            }
#pragma unroll
            for (int i = 0; i < 4; ++i)
#pragma unroll
                for (int j = 0; j < 4; ++j)
                    acc[i][j] += q0[i] * k0[j] + q1[i] * k1[j];
        }
    }

    // ---- phase 2: sigmoid(score/32) into LDS ----
    const float scale = 0.03125f;
#pragma unroll
    for (int i = 0; i < 4; ++i)
#pragma unroll
        for (int j = 0; j < 4; ++j) {
            const float xv = acc[i][j] * scale;
            scb[sy + i][sx + j] = 1.0f / (1.0f + __expf(-xv));
        }
    __syncthreads();

    // ---- phase 3: out = scores @ v, overwrite q slot ----
    const int fcol = tid * 4;
#pragma unroll 1
    for (int gIdx = 0; gIdx < 4; ++gIdx) {
        float o[16][4];
#pragma unroll
        for (int i = 0; i < 16; ++i)
#pragma unroll
            for (int j = 0; j < 4; ++j) o[i][j] = 0.0f;

        for (int t = 0; t < 64; ++t) {
            const ushort4 va = *(const ushort4*)(vbase + (size_t)t * HWHW + fcol);
            const float v0 = bf2f(va.x), v1 = bf2f(va.y), v2 = bf2f(va.z), v3 = bf2f(va.w);
#pragma unroll
            for (int i = 0; i < 16; ++i) {
                const float a = scb[gIdx * 16 + i][t];
                o[i][0] += a * v0;
                o[i][1] += a * v1;
                o[i][2] += a * v2;
                o[i][3] += a * v3;
            }
        }
#pragma unroll
        for (int i = 0; i < 16; ++i) {
            const int srow = gIdx * 16 + i;
            ushort4 u;
            u.x = f2bf(o[i][0]);
            u.y = f2bf(o[i][1]);
            u.z = f2bf(o[i][2]);
            u.w = f2bf(o[i][3]);
            *(ushort4*)(qbase + (size_t)srow * HWHW + fcol) = u;
        }
    }
}

// ---------------------------------------------------------------------------
// Kernel 3: final conv (Cd=32 -> C=64), bf16 in (q slot), fp32 out.
// Grid: (B*S, 8) — 8 out-channels per block.
// ---------------------------------------------------------------------------
__global__ __launch_bounds__(256) void conv_out_kernel(
    const ushort_t* __restrict__ att,
    const float* __restrict__ wo, const float* __restrict__ bo,
    float* __restrict__ out)
{
    __shared__ float xs[34][34];

    const int tid = threadIdx.x;
    const int bs  = blockIdx.x;
    const int b   = bs >> 6;
    const int s   = bs & 63;
    const int cob = blockIdx.y * 8;

    for (int i = tid; i < 34 * 34; i += 256) ((float*)xs)[i] = 0.0f;

    float acc[8][4];
#pragma unroll
    for (int oc = 0; oc < 8; ++oc)
#pragma unroll
        for (int p = 0; p < 4; ++p) acc[oc][p] = 0.0f;

    const int pix0 = tid * 4;
    const int h0 = pix0 >> 5;
    const int w0 = pix0 & 31;

    for (int c = 0; c < CD; ++c) {
        __syncthreads();
        const ushort4 xa = *(const ushort4*)(att + (((size_t)b * CD + c) * SS + s) * HWHW + pix0);
        xs[h0 + 1][w0 + 1] = bf2f(xa.x);
        xs[h0 + 1][w0 + 2] = bf2f(xa.y);
        xs[h0 + 1][w0 + 3] = bf2f(xa.z);
        xs[h0 + 1][w0 + 4] = bf2f(xa.w);
        __syncthreads();

        float win[3][6];
#pragma unroll
        for (int r = 0; r < 3; ++r)
#pragma unroll
            for (int cc2 = 0; cc2 < 6; ++cc2)
                win[r][cc2] = xs[h0 + r][w0 + cc2];

#pragma unroll
        for (int oc = 0; oc < 8; ++oc) {
            const float* wr = wo + ((size_t)(cob + oc) * CD + c) * 9;
            const float w00 = wr[0], w01 = wr[1], w02 = wr[2];
            const float w10 = wr[3], w11 = wr[4], w12 = wr[5];
            const float w20 = wr[6], w21 = wr[7], w22 = wr[8];
#pragma unroll
            for (int p = 0; p < 4; ++p) {
                float a = acc[oc][p];
                a += w00 * win[0][p + 0] + w01 * win[0][p + 1] + w02 * win[0][p + 2];
                a += w10 * win[1][p + 0] + w11 * win[1][p + 1] + w12 * win[1][p + 2];
                a += w20 * win[2][p + 0] + w21 * win[2][p + 1] + w22 * win[2][p + 2];
                acc[oc][p] = a;
            }
        }
    }

#pragma unroll
    for (int oc = 0; oc < 8; ++oc) {
        const float bias = bo[cob + oc];
        float4 o4;
        o4.x = acc[oc][0] + bias;
        o4.y = acc[oc][1] + bias;
        o4.z = acc[oc][2] + bias;
        o4.w = acc[oc][3] + bias;
        *(float4*)(out + (((size_t)b * CC + cob + oc) * SS + s) * HWHW + pix0) = o4;
    }
}

extern "C" void kernel_launch(void* const* d_in, const int* in_sizes, int n_in,
                              void* d_out, int out_size, void* d_ws, size_t ws_size,
                              hipStream_t stream)
{
    const float* x  = (const float*)d_in[0];
    const float* wq = (const float*)d_in[1];
    const float* bq = (const float*)d_in[2];
    const float* wk = (const float*)d_in[3];
    const float* bk = (const float*)d_in[4];
    const float* wv = (const float*)d_in[5];
    const float* bv = (const float*)d_in[6];
    const float* wo = (const float*)d_in[7];
    const float* bo = (const float*)d_in[8];
    float* out = (float*)d_out;

    ushort_t* qkv = (ushort_t*)d_ws;   // q | k | v, each QELEMS bf16 (192 MiB total)

    dim3 blk(256);
    conv_qkv_kernel<<<dim3(BB * SS, 12), blk, 0, stream>>>(x, wq, bq, wk, bk, wv, bv, qkv);
    attn_kernel<<<dim3(BB * CD), blk, 0, stream>>>(qkv);
    conv_out_kernel<<<dim3(BB * SS, 8), blk, 0, stream>>>(qkv, wo, bo, out);
}

// Round 2
// 1083.484 us; speedup vs baseline: 2.2358x; 2.2358x over previous
//
#include <hip/hip_runtime.h>
#include <hip/hip_bf16.h>

#define BB   16
#define CC   64
#define SS   64
#define HWHW 1024
#define CD   32
#define QELEMS (BB * CD * SS * HWHW) /* 33554432 elems per q/k/v tensor */

typedef unsigned short ushort_t;
typedef __attribute__((ext_vector_type(8)))  short bf16x8;
typedef __attribute__((ext_vector_type(16))) float f32x16;

static __device__ inline float bf2f(ushort_t u) {
    union { float f; unsigned int i; } v;
    v.i = ((unsigned int)u) << 16;
    return v.f;
}
static __device__ inline ushort_t f2bf(float f) {
    union { float f; unsigned int i; } v;
    v.f = f;
    unsigned int x = v.i;
    return (ushort_t)((x + 0x7fffu + ((x >> 16) & 1u)) >> 16);
}

// ---------------------------------------------------------------------------
// Pack weights: Wt[tap][oc(96: q|k|v)][c(64)] bf16 and Wt2[tap][oc(64)][c(32)]
// so MFMA A-fragments (8 consecutive c) are single 16B loads.
// ---------------------------------------------------------------------------
__global__ __launch_bounds__(256) void pack_weights(
    const float* __restrict__ wq, const float* __restrict__ wk,
    const float* __restrict__ wv, const float* __restrict__ wo,
    ushort_t* __restrict__ wt, ushort_t* __restrict__ wt2)
{
    const int d = blockIdx.x * 256 + threadIdx.x;
    if (d < 9 * 96 * 64) {
        const int tap = d / (96 * 64);
        const int rem = d % (96 * 64);
        const int oc  = rem >> 6;
        const int c   = rem & 63;
        const float* wsrc = (oc < 32) ? wq : (oc < 64) ? wk : wv;
        const int ocl = oc & 31;
        wt[d] = f2bf(wsrc[((size_t)ocl * 64 + c) * 9 + tap]);
    }
    const int d2 = d - 9 * 96 * 64;
    if (d2 >= 0 && d2 < 9 * 64 * 32) {
        const int tap = d2 / (64 * 32);
        const int rem = d2 % (64 * 32);
        const int oc  = rem >> 5;
        const int c   = rem & 31;
        wt2[d2] = f2bf(wo[((size_t)oc * 32 + c) * 9 + tap]);
    }
}

// ---------------------------------------------------------------------------
// Kernel 1: fused q/k/v conv via implicit-GEMM MFMA.
// Block: one (b, s, 8-row pixel chunk). M=96 (q|k|v x32ch), N=256 px, K=64x9.
// LDS x tile: pixel-major [row 10][col 34][c 72pad] bf16, halo zero-padded.
// ---------------------------------------------------------------------------
__global__ __launch_bounds__(256) void conv_qkv_mfma(
    const float* __restrict__ x,
    const ushort_t* __restrict__ wt,
    const float* __restrict__ bq, const float* __restrict__ bk,
    const float* __restrict__ bv,
    ushort_t* __restrict__ qkv)
{
    __shared__ ushort_t xs[10][34][72];   // 48960 B

    const int tid   = threadIdx.x;
    const int bs    = blockIdx.x >> 2;
    const int chunk = blockIdx.x & 3;
    const int b     = bs >> 6;
    const int s     = bs & 63;
    const int h0    = chunk * 8;

    // zero the halo columns (col 0 and 33), c in [0,64)
    if (tid < 160) {
        const int r    = tid >> 4;
        const int rest = tid & 15;
        const int col  = (rest >> 3) ? 33 : 0;
        const int c0   = (rest & 7) << 3;
        bf16x8 z = {0, 0, 0, 0, 0, 0, 0, 0};
        *(bf16x8*)&xs[r][col][c0] = z;
    }

    // stage x rows h0-1 .. h0+8 (zeros outside image), fp32 -> bf16 transpose
    const float* xb = x + ((size_t)b * CC * SS + s) * HWHW;
#pragma unroll
    for (int it = 0; it < 20; ++it) {
        const int u  = tid + it * 256;      // 0..5119 = 64c * 10r * 8grp
        const int g  = u & 7;
        const int t2 = u >> 3;              // 0..639
        const int r  = t2 % 10;
        const int c  = t2 / 10;
        const int h  = h0 - 1 + r;
        float4 xv = make_float4(0.f, 0.f, 0.f, 0.f);
        if (h >= 0 && h < 32)
            xv = *(const float4*)(xb + (size_t)c * SS * HWHW + h * 32 + g * 4);
        const int colb = 1 + g * 4;
        xs[r][colb + 0][c] = f2bf(xv.x);
        xs[r][colb + 1][c] = f2bf(xv.y);
        xs[r][colb + 2][c] = f2bf(xv.z);
        xs[r][colb + 3][c] = f2bf(xv.w);
    }
    __syncthreads();

    const int wvid = tid >> 6;
    const int lane = tid & 63;
    const int ln   = lane & 31;
    const int lh   = lane >> 5;
    const int nt0  = wvid * 2;             // wave covers rows nt0, nt0+1 of chunk

    f32x16 acc[3][2];
#pragma unroll
    for (int m = 0; m < 3; ++m)
#pragma unroll
        for (int n = 0; n < 2; ++n)
#pragma unroll
            for (int i = 0; i < 16; ++i) acc[m][n][i] = 0.f;

#pragma unroll 1
    for (int tap = 0; tap < 9; ++tap) {
        const int dh = tap / 3;
        const int dw = tap % 3;
        const ushort_t* wtap = wt + (size_t)tap * 96 * 64;
#pragma unroll
        for (int kc = 0; kc < 4; ++kc) {
            const int c0 = kc * 16 + lh * 8;
            const bf16x8 a0 = *(const bf16x8*)(wtap + (((size_t)ln      ) << 6) + c0);
            const bf16x8 a1 = *(const bf16x8*)(wtap + (((size_t)ln + 32 ) << 6) + c0);
            const bf16x8 a2 = *(const bf16x8*)(wtap + (((size_t)ln + 64 ) << 6) + c0);
            const bf16x8 b0 = *(const bf16x8*)&xs[nt0 + dh    ][ln + dw][c0];
            const bf16x8 b1 = *(const bf16x8*)&xs[nt0 + 1 + dh][ln + dw][c0];
            acc[0][0] = __builtin_amdgcn_mfma_f32_32x32x16_bf16(a0, b0, acc[0][0], 0, 0, 0);
            acc[0][1] = __builtin_amdgcn_mfma_f32_32x32x16_bf16(a0, b1, acc[0][1], 0, 0, 0);
            acc[1][0] = __builtin_amdgcn_mfma_f32_32x32x16_bf16(a1, b0, acc[1][0], 0, 0, 0);
            acc[1][1] = __builtin_amdgcn_mfma_f32_32x32x16_bf16(a1, b1, acc[1][1], 0, 0, 0);
            acc[2][0] = __builtin_amdgcn_mfma_f32_32x32x16_bf16(a2, b0, acc[2][0], 0, 0, 0);
            acc[2][1] = __builtin_amdgcn_mfma_f32_32x32x16_bf16(a2, b1, acc[2][1], 0, 0, 0);
        }
    }

    // epilogue: C/D layout col=lane&31 (pixel), row m=(r&3)+8*(r>>2)+4*lh (oc)
    const float* biases[3] = {bq, bk, bv};
#pragma unroll
    for (int mt = 0; mt < 3; ++mt) {
        const float* bptr = biases[mt];
        ushort_t* dst = qkv + (size_t)mt * QELEMS + (((size_t)b * CD) * SS + s) * HWHW;
#pragma unroll
        for (int ntl = 0; ntl < 2; ++ntl) {
            const int gp = (h0 + nt0 + ntl) * 32 + ln;
#pragma unroll
            for (int r = 0; r < 16; ++r) {
                const int m = (r & 3) + 8 * (r >> 2) + 4 * lh;
                const float val = acc[mt][ntl][r] + bptr[m];
                dst[(size_t)m * SS * HWHW + gp] = f2bf(val);
            }
        }
    }
}

// ---------------------------------------------------------------------------
// Kernel 2: per-(b,c) attention (unchanged from round 1).
// ---------------------------------------------------------------------------
__global__ __launch_bounds__(256) void attn_kernel(ushort_t* __restrict__ qkv)
{
    __shared__ float    scb[64][65];
    __shared__ ushort_t qch[64][132];
    __shared__ ushort_t kch[64][132];

    const int tid = threadIdx.x;
    const int bc  = blockIdx.x;
    ushort_t* qbase = qkv + (size_t)bc * SS * HWHW;
    const ushort_t* kbase = qbase + QELEMS;
    const ushort_t* vbase = qbase + 2 * (size_t)QELEMS;

    const int ty = tid >> 4, tx = tid & 15;
    const int sy = ty * 4, sx = tx * 4;

    float acc[4][4];
#pragma unroll
    for (int i = 0; i < 4; ++i)
#pragma unroll
        for (int j = 0; j < 4; ++j) acc[i][j] = 0.0f;

    for (int fc = 0; fc < 8; ++fc) {
        __syncthreads();
#pragma unroll
        for (int u = 0; u < 8; ++u) {
            const int unit = tid + u * 256;
            const int row  = unit >> 5;
            const int col  = (unit & 31) * 4;
            const ushort4 qa = *(const ushort4*)(qbase + (size_t)row * HWHW + fc * 128 + col);
            const ushort4 ka = *(const ushort4*)(kbase + (size_t)row * HWHW + fc * 128 + col);
            *(ushort4*)&qch[row][col] = qa;
            *(ushort4*)&kch[row][col] = ka;
        }
        __syncthreads();

        for (int f = 0; f < 128; f += 2) {
            float q0[4], q1[4], k0[4], k1[4];
#pragma unroll
            for (int i = 0; i < 4; ++i) {
                const unsigned int qp = *(const unsigned int*)&qch[sy + i][f];
                q0[i] = bf2f((ushort_t)(qp & 0xffffu));
                q1[i] = bf2f((ushort_t)(qp >> 16));
                const unsigned int kp = *(const unsigned int*)&kch[sx + i][f];
                k0[i] = bf2f((ushort_t)(kp & 0xffffu));
                k1[i] = bf2f((ushort_t)(kp >> 16));
            }
#pragma unroll
            for (int i = 0; i < 4; ++i)
#pragma unroll
                for (int j = 0; j < 4; ++j)
                    acc[i][j] += q0[i] * k0[j] + q1[i] * k1[j];
        }
    }

    const float scale = 0.03125f;
#pragma unroll
    for (int i = 0; i < 4; ++i)
#pragma unroll
        for (int j = 0; j < 4; ++j) {
            const float xv = acc[i][j] * scale;
            scb[sy + i][sx + j] = 1.0f / (1.0f + __expf(-xv));
        }
    __syncthreads();

    const int fcol = tid * 4;
#pragma unroll 1
    for (int gIdx = 0; gIdx < 4; ++gIdx) {
        float o[16][4];
#pragma unroll
        for (int i = 0; i < 16; ++i)
#pragma unroll
            for (int j = 0; j < 4; ++j) o[i][j] = 0.0f;

        for (int t = 0; t < 64; ++t) {
            const ushort4 va = *(const ushort4*)(vbase + (size_t)t * HWHW + fcol);
            const float v0 = bf2f(va.x), v1 = bf2f(va.y), v2 = bf2f(va.z), v3 = bf2f(va.w);
#pragma unroll
            for (int i = 0; i < 16; ++i) {
                const float a = scb[gIdx * 16 + i][t];
                o[i][0] += a * v0;
                o[i][1] += a * v1;
                o[i][2] += a * v2;
                o[i][3] += a * v3;
            }
        }
#pragma unroll
        for (int i = 0; i < 16; ++i) {
            const int srow = gIdx * 16 + i;
            ushort4 u;
            u.x = f2bf(o[i][0]);
            u.y = f2bf(o[i][1]);
            u.z = f2bf(o[i][2]);
            u.w = f2bf(o[i][3]);
            *(ushort4*)(qbase + (size_t)srow * HWHW + fcol) = u;
        }
    }
}

// ---------------------------------------------------------------------------
// Kernel 3: final conv (Cd=32 -> C=64) via implicit-GEMM MFMA, fp32 out.
// ---------------------------------------------------------------------------
__global__ __launch_bounds__(256) void conv_out_mfma(
    const ushort_t* __restrict__ att,
    const ushort_t* __restrict__ wt2,
    const float* __restrict__ bo,
    float* __restrict__ out)
{
    __shared__ ushort_t xs[10][34][40];   // 27200 B

    const int tid   = threadIdx.x;
    const int bs    = blockIdx.x >> 2;
    const int chunk = blockIdx.x & 3;
    const int b     = bs >> 6;
    const int s     = bs & 63;
    const int h0    = chunk * 8;

    if (tid < 80) {
        const int r    = tid >> 3;
        const int rest = tid & 7;
        const int col  = (rest >> 2) ? 33 : 0;
        const int c0   = (rest & 3) << 3;
        bf16x8 z = {0, 0, 0, 0, 0, 0, 0, 0};
        *(bf16x8*)&xs[r][col][c0] = z;
    }

    const ushort_t* ab = att + ((size_t)b * CD * SS + s) * HWHW;
#pragma unroll
    for (int it = 0; it < 10; ++it) {
        const int u  = tid + it * 256;      // 0..2559 = 32c * 10r * 8grp
        const int g  = u & 7;
        const int t2 = u >> 3;              // 0..319
        const int r  = t2 % 10;
        const int c  = t2 / 10;
        const int h  = h0 - 1 + r;
        ushort4 xv = make_ushort4(0, 0, 0, 0);
        if (h >= 0 && h < 32)
            xv = *(const ushort4*)(ab + (size_t)c * SS * HWHW + h * 32 + g * 4);
        const int colb = 1 + g * 4;
        xs[r][colb + 0][c] = xv.x;
        xs[r][colb + 1][c] = xv.y;
        xs[r][colb + 2][c] = xv.z;
        xs[r][colb + 3][c] = xv.w;
    }
    __syncthreads();

    const int wvid = tid >> 6;
    const int lane = tid & 63;
    const int ln   = lane & 31;
    const int lh   = lane >> 5;
    const int nt0  = wvid * 2;

    f32x16 acc[2][2];
#pragma unroll
    for (int m = 0; m < 2; ++m)
#pragma unroll
        for (int n = 0; n < 2; ++n)
#pragma unroll
            for (int i = 0; i < 16; ++i) acc[m][n][i] = 0.f;

#pragma unroll 1
    for (int tap = 0; tap < 9; ++tap) {
        const int dh = tap / 3;
        const int dw = tap % 3;
        const ushort_t* wtap = wt2 + (size_t)tap * 64 * 32;
#pragma unroll
        for (int kc = 0; kc < 2; ++kc) {
            const int c0 = kc * 16 + lh * 8;
            const bf16x8 a0 = *(const bf16x8*)(wtap + (((size_t)ln      ) << 5) + c0);
            const bf16x8 a1 = *(const bf16x8*)(wtap + (((size_t)ln + 32 ) << 5) + c0);
            const bf16x8 b0 = *(const bf16x8*)&xs[nt0 + dh    ][ln + dw][c0];
            const bf16x8 b1 = *(const bf16x8*)&xs[nt0 + 1 + dh][ln + dw][c0];
            acc[0][0] = __builtin_amdgcn_mfma_f32_32x32x16_bf16(a0, b0, acc[0][0], 0, 0, 0);
            acc[0][1] = __builtin_amdgcn_mfma_f32_32x32x16_bf16(a0, b1, acc[0][1], 0, 0, 0);
            acc[1][0] = __builtin_amdgcn_mfma_f32_32x32x16_bf16(a1, b0, acc[1][0], 0, 0, 0);
            acc[1][1] = __builtin_amdgcn_mfma_f32_32x32x16_bf16(a1, b1, acc[1][1], 0, 0, 0);
        }
    }

#pragma unroll
    for (int mt = 0; mt < 2; ++mt) {
        float* dst = out + (((size_t)b * CC + mt * 32) * SS + s) * HWHW;
#pragma unroll
        for (int ntl = 0; ntl < 2; ++ntl) {
            const int gp = (h0 + nt0 + ntl) * 32 + ln;
#pragma unroll
            for (int r = 0; r < 16; ++r) {
                const int m = (r & 3) + 8 * (r >> 2) + 4 * lh;
                dst[(size_t)m * SS * HWHW + gp] = acc[mt][ntl][r] + bo[mt * 32 + m];
            }
        }
    }
}

extern "C" void kernel_launch(void* const* d_in, const int* in_sizes, int n_in,
                              void* d_out, int out_size, void* d_ws, size_t ws_size,
                              hipStream_t stream)
{
    const float* x  = (const float*)d_in[0];
    const float* wq = (const float*)d_in[1];
    const float* bq = (const float*)d_in[2];
    const float* wk = (const float*)d_in[3];
    const float* bk = (const float*)d_in[4];
    const float* wv = (const float*)d_in[5];
    const float* bv = (const float*)d_in[6];
    const float* wo = (const float*)d_in[7];
    const float* bo = (const float*)d_in[8];
    float* out = (float*)d_out;

    ushort_t* qkv = (ushort_t*)d_ws;                                   // 192 MiB
    ushort_t* wt  = (ushort_t*)((char*)d_ws + (size_t)3 * QELEMS * 2); // 108 KiB
    ushort_t* wt2 = wt + 9 * 96 * 64;                                  // 36 KiB

    pack_weights<<<288, 256, 0, stream>>>(wq, wk, wv, wo, wt, wt2);
    conv_qkv_mfma<<<dim3(BB * SS * 4), 256, 0, stream>>>(x, wt, bq, bk, bv, qkv);
    attn_kernel<<<dim3(BB * CD), 256, 0, stream>>>(qkv);
    conv_out_mfma<<<dim3(BB * SS * 4), 256, 0, stream>>>(qkv, wt2, bo, out);
}